// Round 5
// baseline (284.550 us; speedup 1.0000x reference)
//
#include <hip/hip_runtime.h>
#include <hip/hip_bf16.h>

// NT-Xent loss, symmetric, occupancy-first:
//   K2: one WG (512 thr, 8 waves) per (bi<=bj) 256x256 pair-block.
//   Wave w owns 32 rows (A = 16 short8 = 64 VGPR only -> ~3 waves/SIMD vs R4's 1).
//   B: 64-col LDS tiles, double-buffered, global_load_lds w=16, XOR-swizzled
//   (R4-validated scheme, 0 bank conflicts). Two acc chains per wave (col halves)
//   for MFMA ILP. exp accumulated to rowsum[i] (regs) and rowsum[j] (colsum LDS).
// R4 evidence: unified VGPR+AGPR ~280 => 1 wave/SIMD, 19% occupancy, every pipe
// <36% busy => latency-bound. This round trades LDS-read amortization for 3x
// occupancy.

typedef __attribute__((ext_vector_type(8)))  short  short8;   // 8 x bf16 (4 VGPR)
typedef __attribute__((ext_vector_type(16))) float  f32x16;   // 32x32 MFMA acc
typedef __attribute__((ext_vector_type(4)))  unsigned short u16x4;

#define D 256           // feature dim (K)
#define TEMP_INV 10.0f

typedef __attribute__((address_space(1))) const unsigned int as1_u32;
typedef __attribute__((address_space(3))) unsigned int       as3_u32;

__device__ __forceinline__ void gload_lds16(const void* g, void* l) {
    __builtin_amdgcn_global_load_lds((as1_u32*)g, (as3_u32*)l, 16, 0, 0);
}

__device__ __forceinline__ unsigned short f2bf(float x) {
    unsigned int u = __float_as_uint(x);
    u += 0x7FFFu + ((u >> 16) & 1u);          // round-to-nearest-even
    return (unsigned short)(u >> 16);
}

// ---------------- K1: normalize + cast to bf16, zero reduction ws ----------------
__global__ __launch_bounds__(256) void k_norm(const float* __restrict__ z1,
                                              const float* __restrict__ z2,
                                              unsigned short* __restrict__ zn,
                                              float* __restrict__ red, int N) {
    const int wv   = threadIdx.x >> 6;
    const int lane = threadIdx.x & 63;
    const int row  = blockIdx.x * 4 + wv;                 // one wave per row
    const float* src = (row < N) ? (z1 + (size_t)row * D)
                                 : (z2 + (size_t)(row - N) * D);
    float4 v = *(const float4*)(src + lane * 4);          // 64 lanes x 4 = 256
    float s = v.x * v.x + v.y * v.y + v.z * v.z + v.w * v.w;
    #pragma unroll
    for (int off = 1; off < 64; off <<= 1) s += __shfl_xor(s, off);
    float inv = 1.0f / fmaxf(sqrtf(s), 1e-6f);
    u16x4 o;
    o.x = f2bf(v.x * inv); o.y = f2bf(v.y * inv);
    o.z = f2bf(v.z * inv); o.w = f2bf(v.w * inv);
    *(u16x4*)(zn + (size_t)row * D + lane * 4) = o;

    int tid = blockIdx.x * 256 + threadIdx.x;
    int N2 = 2 * N;
    if (tid <= N2) red[tid] = 0.0f;               // rowsum[0..2N) + possum
}

// ---------------- K2: symmetric fused sim + exp-rowsum + positives ----------------
__global__ __launch_bounds__(512, 3) void k_sim(const unsigned short* __restrict__ zn,
                                                float* __restrict__ rowsum,
                                                float* __restrict__ possum,
                                                int N2) {
    __shared__ __align__(16) char ldsB[2][32768];   // 64 cols x 512 B, double-buffered
    __shared__ float colsum[8][256];                // per-wave column partials

    const int tid  = threadIdx.x;
    const int lane = tid & 63;
    const int w    = tid >> 6;          // wave 0..7
    const int l31  = lane & 31;
    const int hi   = lane >> 5;

    const int NBr = N2 >> 8;            // 64 blocks of 256 rows
    const int nwg = (NBr * (NBr + 1)) >> 1;

    // bijective XCD swizzle (nwg % 8 == 0): contiguous p per XCD -> A-panel L2 reuse
    const int cpx = nwg >> 3;
    const int bid = (int)blockIdx.x;
    const int p   = (bid & 7) * cpx + (bid >> 3);

    // triangular pair decode: p -> (bi, bj), bj >= bi
    int bi = (int)((2.0f * NBr + 1.0f
                    - sqrtf((float)((2 * NBr + 1) * (2 * NBr + 1) - 8 * p))) * 0.5f);
    while ((bi + 1) * NBr - ((bi + 1) * bi) / 2 <= p) ++bi;
    while (bi * NBr - (bi * (bi - 1)) / 2 > p) --bi;
    const int bj = bi + (p - (bi * NBr - (bi * (bi - 1)) / 2));
    const bool diagWG = (bi == bj);
    const bool posWG  = (bj == bi + (NBr >> 1));   // contains the (i, i+N) diagonal

    const int r0 = bi * 256 + w * 32;              // this wave's 32 A rows

    // ---- A panel: a[ks] = zn[r0 + l31][ks*16 + hi*8 .. +8]  (64 VGPRs)
    short8 a[16];
    {
        const unsigned short* pA = zn + (size_t)(r0 + l31) * D + hi * 8;
        #pragma unroll
        for (int ks = 0; ks < 16; ++ks) a[ks] = *(const short8*)(pA + ks * 16);
        #pragma unroll
        for (int ks = 0; ks < 16; ++ks) asm volatile("" : "+v"(a[ks]));  // pin
    }

    // ---- staging offsets (linear LDS dest, inverse-swizzled global source)
    int src_off[4], lds_base[4];
    #pragma unroll
    for (int q = 0; q < 4; ++q) {
        int dl = ((q * 8 + w) * 64 + lane) * 16;   // linear dest byte in 32 KB tile
        int row = dl >> 9;                         // col index 0..63
        src_off[q] = dl ^ ((row & 31) << 4);       // inverse swizzle on source
        lds_base[q] = (q * 8 + w) * 1024;          // wave-uniform base
    }
    const char* Bbase = (const char*)zn + (size_t)bj * 256 * D * 2;  // 512 B/row

#define STAGE(IT, BUF)                                                        \
    {                                                                         \
        const char* tb_ = Bbase + (IT) * 32768;                               \
        _Pragma("unroll")                                                     \
        for (int q = 0; q < 4; ++q)                                           \
            gload_lds16(tb_ + src_off[q], ldsB[BUF] + lds_base[q]);           \
    }

    float ea[16];
    #pragma unroll
    for (int r = 0; r < 16; ++r) ea[r] = 0.0f;
    float posAcc = 0.0f;

    const float SC   = 14.4269504088896341f;   // 10 * log2(e)
    const float CLIP = 1.0f - 1e-6f;

    STAGE(0, 0);
    __syncthreads();

    for (int it = 0; it < 4; ++it) {
        const int cur = it & 1;
        if (it < 3) STAGE(it + 1, cur ^ 1);

        f32x16 acc0, acc1;                       // col halves nf=0,1: 2 indep chains
        #pragma unroll
        for (int r = 0; r < 16; ++r) { acc0[r] = 0.0f; acc1[r] = 0.0f; }

        const char* B = ldsB[cur];
        #pragma unroll
        for (int ks = 0; ks < 16; ++ks) {
            int g = ((((ks << 1) | hi) ^ l31) << 4);        // XOR bank swizzle
            short8 b0 = *(const short8*)(B + l31 * 512 + g);
            short8 b1 = *(const short8*)(B + (l31 + 32) * 512 + g);
            acc0 = __builtin_amdgcn_mfma_f32_32x32x16_bf16(a[ks], b0, acc0, 0, 0, 0);
            acc1 = __builtin_amdgcn_mfma_f32_32x32x16_bf16(a[ks], b1, acc1, 0, 0, 0);
        }

        // epilogue: e = exp2(sim*SC - SC); row-acc always; col partials per half.
        // Diag/pos hit: this wave's rows meet cols when it==w>>1, half nf==w&1.
        float cp0 = 0.0f, cp1 = 0.0f;
        const bool hitW = (diagWG | posWG) && (it == (w >> 1));
        #pragma unroll
        for (int r = 0; r < 16; ++r) {
            float s0 = acc0[r], s1 = acc1[r];
            float e0 = __builtin_amdgcn_exp2f(fmaf(s0, SC, -SC));
            float e1 = __builtin_amdgcn_exp2f(fmaf(s1, SC, -SC));
            if (hitW) {
                int crow = (r & 3) + 8 * (r >> 2) + 4 * hi;  // C/D row in 32x32 frag
                if (l31 == crow) {
                    if ((w & 1) == 0) {
                        if (diagWG) e0 = 0.0f;
                        else posAcc += 2.0f * fminf(fmaxf(s0, -CLIP), CLIP);
                    } else {
                        if (diagWG) e1 = 0.0f;
                        else posAcc += 2.0f * fminf(fmaxf(s1, -CLIP), CLIP);
                    }
                }
            }
            ea[r] += e0 + e1;
            cp0 += e0;  cp1 += e1;
        }
        if (!diagWG) {                            // col-side partials (symmetry)
            cp0 += __shfl_xor(cp0, 32);           // fold hi half (same col, other rows)
            cp1 += __shfl_xor(cp1, 32);
            if (lane < 32) {
                colsum[w][it * 64 + l31]      = cp0;
                colsum[w][it * 64 + 32 + l31] = cp1;
            }
        }
        __syncthreads();   // staged tile ready; all reads of cur done
    }

    // ---- row-side flush (rows of slice bi)
    #pragma unroll
    for (int r = 0; r < 16; ++r) {
        float v = ea[r];
        v += __shfl_xor(v, 1);  v += __shfl_xor(v, 2);  v += __shfl_xor(v, 4);
        v += __shfl_xor(v, 8);  v += __shfl_xor(v, 16);
        if (l31 == 0)           // lanes 0 (hi=0) and 32 (hi=1), disjoint rows
            atomicAdd(rowsum + r0 + (r & 3) + 8 * (r >> 2) + 4 * hi, v);
    }

    // ---- col-side flush (rows of slice bj, via symmetry; skip for diag blocks)
    if (!diagWG && tid < 256) {
        float cv = 0.0f;
        #pragma unroll
        for (int w8 = 0; w8 < 8; ++w8) cv += colsum[w8][tid];
        atomicAdd(rowsum + bj * 256 + tid, cv);
    }

    // ---- positives
    if (posWG) {
        #pragma unroll
        for (int off = 1; off < 64; off <<= 1) posAcc += __shfl_xor(posAcc, off);
        if (lane == 0) atomicAdd(possum, posAcc);
    }
#undef STAGE
}

// ---------------- K3: final scalar reduction ----------------
__global__ __launch_bounds__(1024) void k_final(const float* __restrict__ red,
                                                float* __restrict__ out, int N2) {
    __shared__ float sm[16];
    float s = 0.0f;
    for (int i = threadIdx.x; i < N2; i += 1024)
        s += __logf(red[i]);                 // lse_i = log(rowsum_i) + 10
    #pragma unroll
    for (int off = 1; off < 64; off <<= 1) s += __shfl_xor(s, off);
    const int wv = threadIdx.x >> 6, lane = threadIdx.x & 63;
    if (lane == 0) sm[wv] = s;
    __syncthreads();
    if (threadIdx.x == 0) {
        float t = 0.0f;
        #pragma unroll
        for (int w = 0; w < 16; ++w) t += sm[w];
        float possum = red[N2];
        out[0] = (t + 10.0f * (float)N2 - possum * TEMP_INV) / (float)N2;
    }
}

extern "C" void kernel_launch(void* const* d_in, const int* in_sizes, int n_in,
                              void* d_out, int out_size, void* d_ws, size_t ws_size,
                              hipStream_t stream) {
    const float* z1 = (const float*)d_in[0];
    const float* z2 = (const float*)d_in[1];
    const int N  = in_sizes[0] / D;      // 8192
    const int N2 = 2 * N;                // 16384
    const int NBr = N2 / 256;            // 64
    const int nwg = (NBr * (NBr + 1)) / 2;   // 2080

    unsigned short* zn = (unsigned short*)d_ws;                       // N2 x D bf16 (8 MB)
    float* red = (float*)((char*)d_ws + (size_t)N2 * D * sizeof(unsigned short));
    // red[0..N2) = rowsum, red[N2] = possum

    k_norm<<<N2 / 4, 256, 0, stream>>>(z1, z2, zn, red, N);
    k_sim<<<nwg, 512, 0, stream>>>(zn, red, red + N2, N2);
    k_final<<<1, 1024, 0, stream>>>(red, (float*)d_out, N2);
}

// Round 7
// 235.941 us; speedup vs baseline: 1.2060x; 1.2060x over previous
//
#include <hip/hip_runtime.h>
#include <hip/hip_bf16.h>

// NT-Xent loss, symmetric, pipelined:
//   K2: one WG (512 thr, 8 waves) per (bi<=bj) 256x256 pair-block.
//   Wave w owns 32 rows (A in regs); B: 64-col LDS tiles, double-buffered via
//   global_load_lds w=16 + XOR swizzle (R4/R5-validated, 0 bank conflicts).
//   R6: counted-vmcnt pipeline (T3/T4-lite) — raw s_barrier + s_waitcnt vmcnt(4)
//   so next-tile stage loads stay in flight across the barrier (R4/R5's
//   __syncthreads drained vmcnt(0) every iter = serialized stage latency).
//   launch_bounds(512,2): R5's (512,3) caused scratch spills (WRITE_SIZE 218MB).
//   T5 setprio around MFMA cluster.

typedef __attribute__((ext_vector_type(8)))  short  short8;   // 8 x bf16 (4 VGPR)
typedef __attribute__((ext_vector_type(16))) float  f32x16;   // 32x32 MFMA acc
typedef __attribute__((ext_vector_type(4)))  unsigned short u16x4;

#define D 256           // feature dim (K)
#define TEMP_INV 10.0f

typedef __attribute__((address_space(1))) const unsigned int as1_u32;
typedef __attribute__((address_space(3))) unsigned int       as3_u32;

__device__ __forceinline__ void gload_lds16(const void* g, void* l) {
    __builtin_amdgcn_global_load_lds((as1_u32*)g, (as3_u32*)l, 16, 0, 0);
}

__device__ __forceinline__ unsigned short f2bf(float x) {
    unsigned int u = __float_as_uint(x);
    u += 0x7FFFu + ((u >> 16) & 1u);          // round-to-nearest-even
    return (unsigned short)(u >> 16);
}

// ---------------- K1: normalize + cast to bf16, zero reduction ws ----------------
__global__ __launch_bounds__(256) void k_norm(const float* __restrict__ z1,
                                              const float* __restrict__ z2,
                                              unsigned short* __restrict__ zn,
                                              float* __restrict__ red, int N) {
    const int wv   = threadIdx.x >> 6;
    const int lane = threadIdx.x & 63;
    const int row  = blockIdx.x * 4 + wv;                 // one wave per row
    const float* src = (row < N) ? (z1 + (size_t)row * D)
                                 : (z2 + (size_t)(row - N) * D);
    float4 v = *(const float4*)(src + lane * 4);          // 64 lanes x 4 = 256
    float s = v.x * v.x + v.y * v.y + v.z * v.z + v.w * v.w;
    #pragma unroll
    for (int off = 1; off < 64; off <<= 1) s += __shfl_xor(s, off);
    float inv = 1.0f / fmaxf(sqrtf(s), 1e-6f);
    u16x4 o;
    o.x = f2bf(v.x * inv); o.y = f2bf(v.y * inv);
    o.z = f2bf(v.z * inv); o.w = f2bf(v.w * inv);
    *(u16x4*)(zn + (size_t)row * D + lane * 4) = o;

    int tid = blockIdx.x * 256 + threadIdx.x;
    int N2 = 2 * N;
    if (tid <= N2) red[tid] = 0.0f;               // rowsum[0..2N) + possum
}

// ---------------- K2: symmetric fused sim + exp-rowsum + positives ----------------
__global__ __launch_bounds__(512, 2) void k_sim(const unsigned short* __restrict__ zn,
                                                float* __restrict__ rowsum,
                                                float* __restrict__ possum,
                                                int N2) {
    __shared__ __align__(16) char ldsB[2][32768];   // 64 cols x 512 B, double-buffered
    __shared__ float colsum[8][256];                // per-wave column partials

    const int tid  = threadIdx.x;
    const int lane = tid & 63;
    const int w    = tid >> 6;          // wave 0..7
    const int l31  = lane & 31;
    const int hi   = lane >> 5;

    const int NBr = N2 >> 8;            // 64 blocks of 256 rows
    const int nwg = (NBr * (NBr + 1)) >> 1;

    // bijective XCD swizzle (nwg % 8 == 0): contiguous p per XCD -> A-panel L2 reuse
    const int cpx = nwg >> 3;
    const int bid = (int)blockIdx.x;
    const int p   = (bid & 7) * cpx + (bid >> 3);

    // triangular pair decode: p -> (bi, bj), bj >= bi
    int bi = (int)((2.0f * NBr + 1.0f
                    - sqrtf((float)((2 * NBr + 1) * (2 * NBr + 1) - 8 * p))) * 0.5f);
    while ((bi + 1) * NBr - ((bi + 1) * bi) / 2 <= p) ++bi;
    while (bi * NBr - (bi * (bi - 1)) / 2 > p) --bi;
    const int bj = bi + (p - (bi * NBr - (bi * (bi - 1)) / 2));
    const bool diagWG = (bi == bj);
    const bool posWG  = (bj == bi + (NBr >> 1));   // contains the (i, i+N) diagonal

    const int r0 = bi * 256 + w * 32;              // this wave's 32 A rows

    // ---- A panel: a[ks] = zn[r0 + l31][ks*16 + hi*8 .. +8]  (64 VGPRs)
    short8 a[16];
    {
        const unsigned short* pA = zn + (size_t)(r0 + l31) * D + hi * 8;
        #pragma unroll
        for (int ks = 0; ks < 16; ++ks) a[ks] = *(const short8*)(pA + ks * 16);
        #pragma unroll
        for (int ks = 0; ks < 16; ++ks) asm volatile("" : "+v"(a[ks]));  // pin
    }

    // ---- staging offsets (linear LDS dest, inverse-swizzled global source)
    int src_off[4], lds_base[4];
    #pragma unroll
    for (int q = 0; q < 4; ++q) {
        int dl = ((q * 8 + w) * 64 + lane) * 16;   // linear dest byte in 32 KB tile
        int row = dl >> 9;                         // col index 0..63
        src_off[q] = dl ^ ((row & 31) << 4);       // inverse swizzle on source
        lds_base[q] = (q * 8 + w) * 1024;          // wave-uniform base
    }
    const char* Bbase = (const char*)zn + (size_t)bj * 256 * D * 2;  // 512 B/row

#define STAGE(IT, BUF)                                                        \
    {                                                                         \
        const char* tb_ = Bbase + (IT) * 32768;                               \
        _Pragma("unroll")                                                     \
        for (int q = 0; q < 4; ++q)                                           \
            gload_lds16(tb_ + src_off[q], ldsB[BUF] + lds_base[q]);           \
    }

    float ea[16];
    #pragma unroll
    for (int r = 0; r < 16; ++r) ea[r] = 0.0f;
    float posAcc = 0.0f;

    const float SC   = 14.4269504088896341f;   // 10 * log2(e)
    const float CLIP = 1.0f - 1e-6f;

    // ---- prologue: tile 0 staged and drained
    STAGE(0, 0);
    asm volatile("s_waitcnt vmcnt(0)" ::: "memory");
    __builtin_amdgcn_s_barrier();
    __builtin_amdgcn_sched_barrier(0);

    #pragma unroll
    for (int it = 0; it < 4; ++it) {
        const int cur = it & 1;
        if (it == 0) {
            STAGE(1, 1);                          // buf0 already ready (prologue)
        } else {
            if (it < 3) {
                STAGE(it + 1, cur ^ 1);           // 4 new loads in flight
                asm volatile("s_waitcnt vmcnt(4)" ::: "memory");  // cur's 4 done
            } else {
                asm volatile("s_waitcnt vmcnt(0)" ::: "memory");  // last tile done
            }
            __builtin_amdgcn_s_barrier();         // all waves agree cur is ready
        }
        __builtin_amdgcn_sched_barrier(0);

        f32x16 acc0, acc1;                        // col halves: 2 indep chains
        #pragma unroll
        for (int r = 0; r < 16; ++r) { acc0[r] = 0.0f; acc1[r] = 0.0f; }

        const char* B = ldsB[cur];
        __builtin_amdgcn_s_setprio(1);
        #pragma unroll
        for (int ks = 0; ks < 16; ++ks) {
            int g = ((((ks << 1) | hi) ^ l31) << 4);        // XOR bank swizzle
            short8 b0 = *(const short8*)(B + l31 * 512 + g);
            short8 b1 = *(const short8*)(B + (l31 + 32) * 512 + g);
            acc0 = __builtin_amdgcn_mfma_f32_32x32x16_bf16(a[ks], b0, acc0, 0, 0, 0);
            acc1 = __builtin_amdgcn_mfma_f32_32x32x16_bf16(a[ks], b1, acc1, 0, 0, 0);
        }
        __builtin_amdgcn_s_setprio(0);

        // epilogue: e = exp2(sim*SC - SC); row-acc always; col partials per half.
        float cp0 = 0.0f, cp1 = 0.0f;
        const bool hitW = (diagWG | posWG) && (it == (w >> 1));
        #pragma unroll
        for (int r = 0; r < 16; ++r) {
            float s0 = acc0[r], s1 = acc1[r];
            float e0 = __builtin_amdgcn_exp2f(fmaf(s0, SC, -SC));
            float e1 = __builtin_amdgcn_exp2f(fmaf(s1, SC, -SC));
            if (hitW) {
                int crow = (r & 3) + 8 * (r >> 2) + 4 * hi;  // C/D row in 32x32 frag
                if (l31 == crow) {
                    if ((w & 1) == 0) {
                        if (diagWG) e0 = 0.0f;
                        else posAcc += 2.0f * fminf(fmaxf(s0, -CLIP), CLIP);
                    } else {
                        if (diagWG) e1 = 0.0f;
                        else posAcc += 2.0f * fminf(fmaxf(s1, -CLIP), CLIP);
                    }
                }
            }
            ea[r] += e0 + e1;
            cp0 += e0;  cp1 += e1;
        }
        if (!diagWG) {                            // col-side partials (symmetry)
            cp0 += __shfl_xor(cp0, 32);           // fold hi half (same col, other rows)
            cp1 += __shfl_xor(cp1, 32);
            if (lane < 32) {
                colsum[w][it * 64 + l31]      = cp0;
                colsum[w][it * 64 + 32 + l31] = cp1;
            }
        }
        __builtin_amdgcn_s_barrier();   // all reads of cur done before overwrite
        __builtin_amdgcn_sched_barrier(0);
    }

    // make colsum writes visible across waves (raw barriers don't drain lgkm)
    __syncthreads();

    // ---- row-side flush (rows of slice bi)
    #pragma unroll
    for (int r = 0; r < 16; ++r) {
        float v = ea[r];
        v += __shfl_xor(v, 1);  v += __shfl_xor(v, 2);  v += __shfl_xor(v, 4);
        v += __shfl_xor(v, 8);  v += __shfl_xor(v, 16);
        if (l31 == 0)           // lanes 0 (hi=0) and 32 (hi=1), disjoint rows
            atomicAdd(rowsum + r0 + (r & 3) + 8 * (r >> 2) + 4 * hi, v);
    }

    // ---- col-side flush (rows of slice bj, via symmetry; skip for diag blocks)
    if (!diagWG && tid < 256) {
        float cv = 0.0f;
        #pragma unroll
        for (int w8 = 0; w8 < 8; ++w8) cv += colsum[w8][tid];
        atomicAdd(rowsum + bj * 256 + tid, cv);
    }

    // ---- positives
    if (posWG) {
        #pragma unroll
        for (int off = 1; off < 64; off <<= 1) posAcc += __shfl_xor(posAcc, off);
        if (lane == 0) atomicAdd(possum, posAcc);
    }
#undef STAGE
}

// ---------------- K3: final scalar reduction ----------------
__global__ __launch_bounds__(1024) void k_final(const float* __restrict__ red,
                                                float* __restrict__ out, int N2) {
    __shared__ float sm[16];
    float s = 0.0f;
    for (int i = threadIdx.x; i < N2; i += 1024)
        s += __logf(red[i]);                 // lse_i = log(rowsum_i) + 10
    #pragma unroll
    for (int off = 1; off < 64; off <<= 1) s += __shfl_xor(s, off);
    const int wv = threadIdx.x >> 6, lane = threadIdx.x & 63;
    if (lane == 0) sm[wv] = s;
    __syncthreads();
    if (threadIdx.x == 0) {
        float t = 0.0f;
        #pragma unroll
        for (int w = 0; w < 16; ++w) t += sm[w];
        float possum = red[N2];
        out[0] = (t + 10.0f * (float)N2 - possum * TEMP_INV) / (float)N2;
    }
}

extern "C" void kernel_launch(void* const* d_in, const int* in_sizes, int n_in,
                              void* d_out, int out_size, void* d_ws, size_t ws_size,
                              hipStream_t stream) {
    const float* z1 = (const float*)d_in[0];
    const float* z2 = (const float*)d_in[1];
    const int N  = in_sizes[0] / D;      // 8192
    const int N2 = 2 * N;                // 16384
    const int NBr = N2 / 256;            // 64
    const int nwg = (NBr * (NBr + 1)) / 2;   // 2080

    unsigned short* zn = (unsigned short*)d_ws;                       // N2 x D bf16 (8 MB)
    float* red = (float*)((char*)d_ws + (size_t)N2 * D * sizeof(unsigned short));
    // red[0..N2) = rowsum, red[N2] = possum

    k_norm<<<N2 / 4, 256, 0, stream>>>(z1, z2, zn, red, N);
    k_sim<<<nwg, 512, 0, stream>>>(zn, red, red + N2, N2);
    k_final<<<1, 1024, 0, stream>>>(red, (float*)d_out, N2);
}